// Round 1
// baseline (8555.907 us; speedup 1.0000x reference)
//
#include <hip/hip_runtime.h>
#include <hip/hip_cooperative_groups.h>
#include <math.h>

namespace cg = cooperative_groups;

typedef unsigned short u16;
typedef __bf16 bf16x8 __attribute__((ext_vector_type(8)));
typedef float f32x4 __attribute__((ext_vector_type(4)));
typedef unsigned short u16x8 __attribute__((ext_vector_type(8)));
typedef int i32x4 __attribute__((ext_vector_type(4)));

#define NBLK 256
#define NTHR 512         // 8 waves = 2 K-split teams x 4 waves -> 2 waves/SIMD
#define BB 1024
#define TT 256
#define EE 512
#define UU 1024
#define K0 1536          // A0 row: [emb(512) | h0(1024)]
#define K1 2048          // A1 row: [h0'(1024) | h1(1024)]
#define NK0 48           // K0/32
#define NK1 64           // K1/32
#define HN0 ((size_t)BB * K0)
#define HN1 ((size_t)BB * K1)
#define LDS_BYTES 163840 // 128KB weights (2 frag-cols, L1 job) + 32KB f32 team partials

// bar layout (ints)
#define ROSTER_BASE 0            // [0..7] per-XCD block count
#define FLAG_BASE 32             // 8 * 256 arrival flags
#define EPOCH_BASE (32 + 2048)   // 8 epochs, 32-int stride
#define BAR_INTS 2560

#define AUX_SC0 1        // bypass L1, served by local L2

__device__ i32x4 llvm_amdgcn_raw_buffer_load_i32x4(i32x4 srsrc, int voffset, int soffset,
                                                   int aux) __asm("llvm.amdgcn.raw.buffer.load.v4i32");

__device__ __forceinline__ i32x4 make_srd(const void* p) {
  union { const void* p; int i[2]; } u; u.p = p;
  i32x4 r; r.x = u.i[0]; r.y = u.i[1]; r.z = -1; r.w = 0x00020000;
  return r;
}

__device__ __forceinline__ u16 f2bf(float f) {
  unsigned u = __builtin_bit_cast(unsigned, f);
  u += 0x7fffu + ((u >> 16) & 1u);
  return (u16)(u >> 16);
}
__device__ __forceinline__ float bf2f(u16 h) {
  return __builtin_bit_cast(float, ((unsigned)h) << 16);
}
__device__ __forceinline__ float fast_tanh(float x) {
  x = fminf(fmaxf(x, -15.f), 15.f);
  float e = __expf(2.f * x);
  return (e - 1.f) / (e + 1.f);
}

// weight transpose + MFMA-fragment swizzle (r2/r3-verified layout):
// elem g = (cb*NK + kt)*64 + lane (8 u16 each); value = Wfull[k][n],
// n = cb*16 + (lane&15), k = kt*32 + (lane>>4)*8 + e
template<int K, int KLOW>
__device__ __forceinline__ void wfill(u16* __restrict__ Wt,
    const float* __restrict__ Wl, const float* __restrict__ Wh, int gstart) {
  constexpr int NK = K / 32;
  constexpr int NG = 1024 * K / 8;
  for (int g = gstart; g < NG; g += NBLK * NTHR) {
    const int lane = g & 63;
    const int r = g >> 6;
    const int kt = r % NK;
    const int cb = r / NK;
    const int n = cb * 16 + (lane & 15);
    const int kb = kt * 32 + (lane >> 4) * 8;
    u16x8 o;
#pragma unroll
    for (int e = 0; e < 8; ++e) {
      const int k = kb + e;
      const float v = (k < KLOW) ? Wl[(size_t)k * UU + n] : Wh[(size_t)(k - KLOW) * UU + n];
      o[e] = f2bf(v);
    }
    *(u16x8*)(Wt + (size_t)g * 8) = o;
  }
}

// XCD-local barrier from r3-proven primitives: agent-scope flags + leader + epoch.
// Deadlock-proof: waits for measured nx arrivals; guarded polls bail instead of hanging.
__device__ __forceinline__ void xbar(int* __restrict__ bar, int xcc, int slot, int nx,
                                     int tgt, int tid) {
  __syncthreads();   // all waves' stores drained (vmcnt0) before arrival
  if (tid < 64) {
    if (tid == 0)
      __hip_atomic_store(&bar[FLAG_BASE + xcc * 256 + slot], tgt,
                         __ATOMIC_RELAXED, __HIP_MEMORY_SCOPE_AGENT);
    if (slot == 0) {
      for (int base = 0; base < nx; base += 64) {
        const int i = base + tid;
        const bool act = (i < nx);
        int guard = 0;
        bool done = false;
        do {
          int v = act ? __hip_atomic_load(&bar[FLAG_BASE + xcc * 256 + i],
                                          __ATOMIC_RELAXED, __HIP_MEMORY_SCOPE_AGENT)
                      : tgt;
          done = __all(v >= tgt) != 0;
        } while (!done && ++guard < 300000);
      }
      if (tid == 0)
        __hip_atomic_store(&bar[EPOCH_BASE + xcc * 32], tgt,
                           __ATOMIC_RELAXED, __HIP_MEMORY_SCOPE_AGENT);
    } else if (tid == 0) {
      int guard = 0;
      while (__hip_atomic_load(&bar[EPOCH_BASE + xcc * 32],
                               __ATOMIC_RELAXED, __HIP_MEMORY_SCOPE_AGENT) < tgt
             && ++guard < 600000)
        __builtin_amdgcn_s_sleep(8);
    }
  }
  __syncthreads();
}

// one K-step's operand set: 24 VGPRs (a0,a1: 8; b0-b3: 16)
struct Ops { i32x4 a0, a1; u16x8 b0, b1, b2, b3; };

template<int K>
__device__ __forceinline__ Ops ld_ops(const i32x4& srdA, int voA,
    const u16* __restrict__ bA, const u16* __restrict__ bB, int lo, int kt) {
  constexpr int NK = K / 32;
  Ops o;
  o.a0 = llvm_amdgcn_raw_buffer_load_i32x4(srdA, voA + kt * 64, 0, AUX_SC0);
  o.a1 = llvm_amdgcn_raw_buffer_load_i32x4(srdA, voA + 16 * K * 2 + kt * 64, 0, AUX_SC0);
  o.b0 = *(const u16x8*)(bA + (size_t)kt * 512 + lo);
  o.b1 = *(const u16x8*)(bA + (size_t)(NK + kt) * 512 + lo);
  o.b2 = *(const u16x8*)(bB + (size_t)kt * 512 + lo);
  o.b3 = *(const u16x8*)(bB + (size_t)(NK + kt) * 512 + lo);
  return o;
}

__device__ __forceinline__ void mfma8(const Ops& o, f32x4 (&acc)[2][4]) {
  bf16x8 fa0 = __builtin_bit_cast(bf16x8, o.a0);
  bf16x8 fa1 = __builtin_bit_cast(bf16x8, o.a1);
  bf16x8 fb0 = __builtin_bit_cast(bf16x8, o.b0);
  bf16x8 fb1 = __builtin_bit_cast(bf16x8, o.b1);
  bf16x8 fb2 = __builtin_bit_cast(bf16x8, o.b2);
  bf16x8 fb3 = __builtin_bit_cast(bf16x8, o.b3);
  acc[0][0] = __builtin_amdgcn_mfma_f32_16x16x32_bf16(fa0, fb0, acc[0][0], 0, 0, 0);
  acc[0][1] = __builtin_amdgcn_mfma_f32_16x16x32_bf16(fa0, fb1, acc[0][1], 0, 0, 0);
  acc[0][2] = __builtin_amdgcn_mfma_f32_16x16x32_bf16(fa0, fb2, acc[0][2], 0, 0, 0);
  acc[0][3] = __builtin_amdgcn_mfma_f32_16x16x32_bf16(fa0, fb3, acc[0][3], 0, 0, 0);
  acc[1][0] = __builtin_amdgcn_mfma_f32_16x16x32_bf16(fa1, fb0, acc[1][0], 0, 0, 0);
  acc[1][1] = __builtin_amdgcn_mfma_f32_16x16x32_bf16(fa1, fb1, acc[1][1], 0, 0, 0);
  acc[1][2] = __builtin_amdgcn_mfma_f32_16x16x32_bf16(fa1, fb2, acc[1][2], 0, 0, 0);
  acc[1][3] = __builtin_amdgcn_mfma_f32_16x16x32_bf16(fa1, fb3, acc[1][3], 0, 0, 0);
}

// C-partial[128x64] over kt in [kt0,ktn): depth-4 software pipeline.
// Named-register rotation (no runtime-indexed arrays -> stays in VGPRs);
// loads for kt+3 issue BEFORE the MFMAs of kt, so 3 iterations of VMEM
// latency overlap compute instead of serializing per unroll-group.
template<int K>
__device__ __forceinline__ void gemm2(const i32x4& srdA, int voA,
    const u16* __restrict__ bA, const u16* __restrict__ bB, int lane,
    int kt0, int ktn, f32x4 (&acc)[2][4]) {
  const int lo = lane * 8;
  Ops q0 = ld_ops<K>(srdA, voA, bA, bB, lo, kt0);
  Ops q1 = ld_ops<K>(srdA, voA, bA, bB, lo, kt0 + 1);
  Ops q2 = ld_ops<K>(srdA, voA, bA, bB, lo, kt0 + 2);
#pragma unroll 4
  for (int kt = kt0; kt < ktn - 3; ++kt) {
    Ops q3 = ld_ops<K>(srdA, voA, bA, bB, lo, kt + 3);
    mfma8(q0, acc);
    q0 = q1; q1 = q2; q2 = q3;
  }
  mfma8(q0, acc);
  mfma8(q1, acc);
  mfma8(q2, acc);
}

// layer-0 job jl (0..15): issue emb(tk+1) gather, K-split GEMM of h0'(tk),
// LDS-reduce team partials, epilogue by team 0.
__device__ __forceinline__ void do_l0(int tk, int xcc, int jl, bool uselds,
    u16* ldsm, const u16* __restrict__ Wt0,
    const int* __restrict__ inputs, const float* __restrict__ emb,
    const float* __restrict__ b0, u16* __restrict__ A0, u16* __restrict__ A1,
    int tid)
{
  const int lane = tid & 63, wv = (tid >> 6) & 3, q = lane >> 4, l16 = lane & 15;
  const int team = tid >> 8;       // 0: kt [0,24), 1: kt [24,48)
  const int ltid = tid & 255;
  const int c0 = jl * 64;
  f32x4* part = (f32x4*)(ldsm + 65536);   // byte offset 131072

  // T14: issue emb gather loads now, convert+store after the GEMM
  f32x4 f0, f1;
  int egrow = 0, ec = 0;
  const bool do_emb = (tk < TT - 1);
  if (do_emb) {
    egrow = xcc * 128 + jl * 8 + (tid >> 6);
    ec = (tid & 63) * 8;
    const int idx = inputs[egrow * TT + tk + 1];
    const f32x4* s = (const f32x4*)(emb + (size_t)idx * EE + ec);
    f0 = s[0]; f1 = s[1];
  }
  if (tk < TT) {
    f32x4 acc[2][4];
#pragma unroll
    for (int i = 0; i < 2; ++i)
#pragma unroll
      for (int n = 0; n < 4; ++n) acc[i][n] = (f32x4){0.f, 0.f, 0.f, 0.f};
    i32x4 srdA = make_srd(A0 + (size_t)(tk & 1) * HN0);
    const int voA = ((xcc * 128 + wv * 32 + l16) * K0 + q * 8) * 2;
    const int kt0 = team * (NK0 / 2), ktn = kt0 + NK0 / 2;
    const u16* bB = Wt0 + (size_t)(c0 / 16 + 2) * NK0 * 512;
    const u16* bA = uselds ? (const u16*)ldsm
                           : Wt0 + (size_t)(c0 / 16) * NK0 * 512;
    gemm2<K0>(srdA, voA, bA, bB, lane, kt0, ktn, acc);
    if (do_emb) {
      u16x8 oa;
#pragma unroll
      for (int j = 0; j < 4; ++j) { oa[j] = f2bf(f0[j]); oa[j + 4] = f2bf(f1[j]); }
      *(u16x8*)(A0 + (size_t)((tk + 1) & 1) * HN0 + (size_t)egrow * K0 + ec) = oa;
    }
    if (team) {
#pragma unroll
      for (int i = 0; i < 2; ++i)
#pragma unroll
        for (int n = 0; n < 4; ++n) part[(i * 4 + n) * 256 + ltid] = acc[i][n];
    }
    __syncthreads();
    if (!team) {
      u16* d1 = A1 + (size_t)(tk & 1) * HN1;              // h0' -> layer-1 input
      u16* d2 = A0 + (size_t)((tk + 1) & 1) * HN0 + 512;  // h0 recurrent
#pragma unroll
      for (int i = 0; i < 2; ++i)
#pragma unroll
        for (int n = 0; n < 4; ++n) acc[i][n] += part[(i * 4 + n) * 256 + ltid];
#pragma unroll
      for (int n = 0; n < 4; ++n) {
        const int col = c0 + n * 16 + l16;
        const float bs = b0[col];
#pragma unroll
        for (int i = 0; i < 2; ++i) {
#pragma unroll
          for (int rr = 0; rr < 4; ++rr) {
            const int grow = xcc * 128 + wv * 32 + i * 16 + q * 4 + rr;
            const u16 v = f2bf(fast_tanh(acc[i][n][rr] + bs));
            d1[(size_t)grow * K1 + col] = v;
            d2[(size_t)grow * K0 + col] = v;
          }
        }
      }
    }
    __syncthreads();   // team0 LDS reads done before next job's partial stores
  }
}

// layer-1 job jl (0..15): K-split GEMM of h1(tk-1), LDS-reduce, epilogue team 0.
__device__ __forceinline__ void do_l1(int tk, int xcc, int jl, bool uselds,
    u16* ldsm, const u16* __restrict__ Wt1,
    const float* __restrict__ b1, u16* __restrict__ A1, int tid)
{
  const int lane = tid & 63, wv = (tid >> 6) & 3, q = lane >> 4, l16 = lane & 15;
  const int team = tid >> 8;       // 0: kt [0,32), 1: kt [32,64)
  const int ltid = tid & 255;
  const int c0 = jl * 64;
  f32x4* part = (f32x4*)(ldsm + 65536);
  f32x4 acc[2][4];
#pragma unroll
  for (int i = 0; i < 2; ++i)
#pragma unroll
    for (int n = 0; n < 4; ++n) acc[i][n] = (f32x4){0.f, 0.f, 0.f, 0.f};
  i32x4 srdA = make_srd(A1 + (size_t)((tk - 1) & 1) * HN1);
  const int voA = ((xcc * 128 + wv * 32 + l16) * K1 + q * 8) * 2;
  const int kt0 = team * (NK1 / 2), ktn = kt0 + NK1 / 2;
  const u16* bB = Wt1 + (size_t)(c0 / 16 + 2) * NK1 * 512;
  const u16* bA = uselds ? (const u16*)ldsm
                         : Wt1 + (size_t)(c0 / 16) * NK1 * 512;
  gemm2<K1>(srdA, voA, bA, bB, lane, kt0, ktn, acc);
  if (team) {
#pragma unroll
    for (int i = 0; i < 2; ++i)
#pragma unroll
      for (int n = 0; n < 4; ++n) part[(i * 4 + n) * 256 + ltid] = acc[i][n];
  }
  __syncthreads();
  if (!team) {
    u16* d1 = A1 + (size_t)(tk & 1) * HN1 + 1024;         // h1 recurrent
#pragma unroll
    for (int i = 0; i < 2; ++i)
#pragma unroll
      for (int n = 0; n < 4; ++n) acc[i][n] += part[(i * 4 + n) * 256 + ltid];
#pragma unroll
    for (int n = 0; n < 4; ++n) {
      const int col = c0 + n * 16 + l16;
      const float bs = b1[col];
#pragma unroll
      for (int i = 0; i < 2; ++i) {
#pragma unroll
        for (int rr = 0; rr < 4; ++rr) {
          const int grow = xcc * 128 + wv * 32 + i * 16 + q * 4 + rr;
          d1[(size_t)grow * K1 + col] = f2bf(fast_tanh(acc[i][n][rr] + bs));
        }
      }
    }
  }
  __syncthreads();
}

__global__ __launch_bounds__(NTHR, 2)
void rnn_kernel(const int* __restrict__ inputs, const float* __restrict__ emb,
    const float* __restrict__ W0, const float* __restrict__ U0, const float* __restrict__ b0,
    const float* __restrict__ W1, const float* __restrict__ U1, const float* __restrict__ b1,
    const float* __restrict__ Wout, const float* __restrict__ bout,
    float* __restrict__ out,
    u16* __restrict__ Wt0, u16* __restrict__ Wt1,
    u16* __restrict__ A0, u16* __restrict__ A1, int* __restrict__ bar)
{
  extern __shared__ u16 lds[];
  int* li = (int*)lds;
  cg::grid_group grid = cg::this_grid();
  const int tid = threadIdx.x, bid = blockIdx.x;

  // ---- startup (grid-distributed): weights, emb(0), zero states + barrier area ----
  const int gstart = bid * NTHR + tid;
  wfill<K0, 512>(Wt0, W0, U0, gstart);
  wfill<K1, 1024>(Wt1, W1, U1, gstart);
  for (int g = gstart; g < BB * EE / 8; g += NBLK * NTHR) {
    const int b = g >> 6, seg = g & 63;
    const int idx = inputs[b * TT];
    const f32x4* s = (const f32x4*)(emb + (size_t)idx * EE + seg * 8);
    f32x4 f0 = s[0], f1 = s[1];
    u16x8 o;
#pragma unroll
    for (int j = 0; j < 4; ++j) { o[j] = f2bf(f0[j]); o[j + 4] = f2bf(f1[j]); }
    *(u16x8*)(A0 + (size_t)b * K0 + seg * 8) = o;
  }
  {
    const u16x8 z = {0, 0, 0, 0, 0, 0, 0, 0};
    for (int g = gstart; g < BB * 1024 / 8; g += NBLK * NTHR) {
      const int b = g >> 7, seg = g & 127;
      *(u16x8*)(A0 + (size_t)b * K0 + 512 + seg * 8) = z;      // h0(-1) = 0
      *(u16x8*)(A1 + (size_t)b * K1 + 1024 + seg * 8) = z;     // h1(-1) = 0
    }
  }
  if (bid == 0) for (int i = tid; i < BAR_INTS; i += NTHR) bar[i] = 0;
  grid.sync();

  // ---- roster: true XCD + slot; second sync publishes per-XCD counts ----
  if (tid == 0) {
    const int xc = __builtin_amdgcn_s_getreg((7 << 11) | 20) & 7;   // HW_REG_XCC_ID
    li[0] = xc;
    li[1] = atomicAdd(&bar[ROSTER_BASE + xc], 1);
  }
  __syncthreads();
  const int xcc = li[0], slot = li[1];
  __syncthreads();
  grid.sync();
  if (tid == 0)
    li[0] = __hip_atomic_load(&bar[ROSTER_BASE + xcc],
                              __ATOMIC_RELAXED, __HIP_MEMORY_SCOPE_AGENT);
  __syncthreads();
  const int nx = li[0];
  __syncthreads();

  // ---- primary job's first 2 frag-cols -> LDS ----
  if (slot < 32) {
    const bool pL0 = slot < 16;
    const int cb = (pL0 ? slot : slot - 16) * 4;
    const int NKp = pL0 ? NK0 : NK1;
    const u16x8* s = (const u16x8*)((pL0 ? Wt0 : Wt1) + (size_t)cb * NKp * 512);
    const int nv = 2 * NKp * 64;
    u16x8* d = (u16x8*)lds;
    for (int i = tid; i < nv; i += NTHR) d[i] = s[i];
  }
  __syncthreads();

  // ---- tick loop: jobs 0..15 = layer0 stripes, 16..31 = layer1 stripes (lagged) ----
  for (int tk = 0; tk <= TT; ++tk) {
    for (int job = slot; job < 32; job += nx) {
      const bool uselds = (job == slot);
      if (job < 16) do_l0(tk, xcc, job, uselds, lds, Wt0, inputs, emb, b0, A0, A1, tid);
      else if (tk >= 1) do_l1(tk, xcc, job - 16, uselds, lds, Wt1, b1, A1, tid);
    }
    xbar(bar, xcc, slot, nx, tk + 1, tid);
  }

  // ---- output (slot 0 per XCD): sigmoid(h1(255) @ Wout + bout) for 128 local rows ----
  if (slot == 0) {
    const int lane = tid & 63, w = tid >> 6;   // 8 waves x 16 rows
    i32x4 srdH = make_srd(A1);
    const f32x4* wv = (const f32x4*)(Wout + lane * 16);
    f32x4 w0 = wv[0], w1 = wv[1], w2 = wv[2], w3 = wv[3];
    for (int rr = 0; rr < 16; ++rr) {
      const int grow = xcc * 128 + w * 16 + rr;
      const int vo = (grow * K1 + 1024 + lane * 16) * 2;
      i32x4 hv0 = llvm_amdgcn_raw_buffer_load_i32x4(srdH, vo, 0, AUX_SC0);
      i32x4 hv1 = llvm_amdgcn_raw_buffer_load_i32x4(srdH, vo + 16, 0, AUX_SC0);
      u16x8 lo = __builtin_bit_cast(u16x8, hv0);
      u16x8 hi = __builtin_bit_cast(u16x8, hv1);
      float s = 0.f;
#pragma unroll
      for (int j = 0; j < 4; ++j) {
        s += bf2f(lo[j]) * w0[j];
        s += bf2f(lo[j + 4]) * w1[j];
        s += bf2f(hi[j]) * w2[j];
        s += bf2f(hi[j + 4]) * w3[j];
      }
#pragma unroll
      for (int off = 32; off > 0; off >>= 1) s += __shfl_down(s, off);
      if (lane == 0) out[grow] = 1.f / (1.f + expf(-(s + bout[0])));
    }
  }
}

extern "C" void kernel_launch(void* const* d_in, const int* in_sizes, int n_in,
                              void* d_out, int out_size, void* d_ws, size_t ws_size,
                              hipStream_t stream)
{
  (void)in_sizes; (void)n_in; (void)out_size; (void)ws_size;
  const int*   inputs = (const int*)d_in[0];
  const float* emb    = (const float*)d_in[1];
  const float* W0     = (const float*)d_in[2];
  const float* U0     = (const float*)d_in[3];
  const float* b0     = (const float*)d_in[4];
  const float* W1     = (const float*)d_in[5];
  const float* U1     = (const float*)d_in[6];
  const float* b1     = (const float*)d_in[7];
  const float* Wout   = (const float*)d_in[8];
  const float* bout   = (const float*)d_in[9];
  float* out = (float*)d_out;

  // ws (u16): Wt0 [1024*K0], Wt1 [1024*K1], A0 [2][1024*K0], A1 [2][1024*K1], bar
  u16* Wt0 = (u16*)d_ws;
  u16* Wt1 = Wt0 + (size_t)1024 * K0;
  u16* A0  = Wt1 + (size_t)1024 * K1;
  u16* A1  = A0 + (size_t)2 * 1024 * K0;
  int* bar = (int*)(A1 + (size_t)2 * 1024 * K1);

  static int lds_set = 0;
  if (!lds_set) {
    hipFuncSetAttribute((const void*)rnn_kernel,
                        hipFuncAttributeMaxDynamicSharedMemorySize, LDS_BYTES);
    lds_set = 1;
  }

  void* args[] = { &inputs, &emb, &W0, &U0, &b0, &W1, &U1, &b1, &Wout, &bout,
                   &out, &Wt0, &Wt1, &A0, &A1, &bar };
  hipLaunchCooperativeKernel((void*)rnn_kernel, dim3(NBLK), dim3(NTHR), args, LDS_BYTES, stream);
}

// Round 3
// 7214.138 us; speedup vs baseline: 1.1860x; 1.1860x over previous
//
#include <hip/hip_runtime.h>
#include <hip/hip_cooperative_groups.h>
#include <math.h>

namespace cg = cooperative_groups;

typedef unsigned short u16;
typedef __bf16 bf16x8 __attribute__((ext_vector_type(8)));
typedef float f32x4 __attribute__((ext_vector_type(4)));
typedef unsigned short u16x8 __attribute__((ext_vector_type(8)));
typedef int i32x4 __attribute__((ext_vector_type(4)));

#define NBLK 256
#define NTHR 256
#define BB 1024
#define TT 256
#define EE 512
#define UU 1024
#define K0 1536          // A0 row: [emb(512) | h0(1024)]
#define K1 2048          // A1 row: [h0'(1024) | h1(1024)]
#define NK0 48           // K0/32
#define NK1 64           // K1/32
#define KTL0 32          // L0: bB kt-prefix resident in LDS (of 48)
#define KTL1 16          // L1: bB kt-prefix resident in LDS (of 64)
#define HN0 ((size_t)BB * K0)
#define HN1 ((size_t)BB * K1)
// LDS: bA 2 frag-cols (L0 96KB / L1 128KB) + bB prefix (L0 64KB / L1 32KB) = 160KB
#define LDS_BYTES 163840

// bar layout (ints)
#define ROSTER_BASE 0            // [0..7] per-XCD block count
#define FLAG_BASE 32             // 8 * 256 arrival flags
#define EPOCH_BASE (32 + 2048)   // 8 epochs, 32-int stride
#define BAR_INTS 2560

#define AUX_SC0 1        // bypass L1, served by local L2

__device__ i32x4 llvm_amdgcn_raw_buffer_load_i32x4(i32x4 srsrc, int voffset, int soffset,
                                                   int aux) __asm("llvm.amdgcn.raw.buffer.load.v4i32");

__device__ __forceinline__ i32x4 make_srd(const void* p) {
  union { const void* p; int i[2]; } u; u.p = p;
  i32x4 r; r.x = u.i[0]; r.y = u.i[1]; r.z = -1; r.w = 0x00020000;
  return r;
}

__device__ __forceinline__ u16 f2bf(float f) {
  unsigned u = __builtin_bit_cast(unsigned, f);
  u += 0x7fffu + ((u >> 16) & 1u);
  return (u16)(u >> 16);
}
__device__ __forceinline__ float bf2f(u16 h) {
  return __builtin_bit_cast(float, ((unsigned)h) << 16);
}
__device__ __forceinline__ float fast_tanh(float x) {
  x = fminf(fmaxf(x, -15.f), 15.f);
  float e = __expf(2.f * x);
  return (e - 1.f) / (e + 1.f);
}

// weight transpose + MFMA-fragment swizzle (r2/r3-verified layout):
// elem g = (cb*NK + kt)*64 + lane (8 u16 each); value = Wfull[k][n],
// n = cb*16 + (lane&15), k = kt*32 + (lane>>4)*8 + e
template<int K, int KLOW>
__device__ __forceinline__ void wfill(u16* __restrict__ Wt,
    const float* __restrict__ Wl, const float* __restrict__ Wh, int gstart) {
  constexpr int NK = K / 32;
  constexpr int NG = 1024 * K / 8;
  for (int g = gstart; g < NG; g += NBLK * NTHR) {
    const int lane = g & 63;
    const int r = g >> 6;
    const int kt = r % NK;
    const int cb = r / NK;
    const int n = cb * 16 + (lane & 15);
    const int kb = kt * 32 + (lane >> 4) * 8;
    u16x8 o;
#pragma unroll
    for (int e = 0; e < 8; ++e) {
      const int k = kb + e;
      const float v = (k < KLOW) ? Wl[(size_t)k * UU + n] : Wh[(size_t)(k - KLOW) * UU + n];
      o[e] = f2bf(v);
    }
    *(u16x8*)(Wt + (size_t)g * 8) = o;
  }
}

// XCD-local barrier: agent-scope flags + leader + epoch; guarded polls bail instead of hanging.
__device__ __forceinline__ void xbar(int* __restrict__ bar, int xcc, int slot, int nx,
                                     int tgt, int tid) {
  __syncthreads();   // all waves' stores drained before arrival
  if (tid < 64) {
    if (tid == 0)
      __hip_atomic_store(&bar[FLAG_BASE + xcc * 256 + slot], tgt,
                         __ATOMIC_RELAXED, __HIP_MEMORY_SCOPE_AGENT);
    if (slot == 0) {
      for (int base = 0; base < nx; base += 64) {
        const int i = base + tid;
        const bool act = (i < nx);
        int guard = 0;
        bool done = false;
        do {
          int v = act ? __hip_atomic_load(&bar[FLAG_BASE + xcc * 256 + i],
                                          __ATOMIC_RELAXED, __HIP_MEMORY_SCOPE_AGENT)
                      : tgt;
          done = __all(v >= tgt) != 0;
        } while (!done && ++guard < 300000);
      }
      if (tid == 0)
        __hip_atomic_store(&bar[EPOCH_BASE + xcc * 32], tgt,
                           __ATOMIC_RELAXED, __HIP_MEMORY_SCOPE_AGENT);
    } else if (tid == 0) {
      int guard = 0;
      while (__hip_atomic_load(&bar[EPOCH_BASE + xcc * 32],
                               __ATOMIC_RELAXED, __HIP_MEMORY_SCOPE_AGENT) < tgt
             && ++guard < 600000)
        __builtin_amdgcn_s_sleep(8);
    }
  }
  __syncthreads();
}

// one kt step: 2 A buffer-loads, 4 B pointer-loads (uniform addressing: p + kt*512 + lo),
// 8 MFMA. Identical per-iteration structure to the r0-proven gemm2 body.
template<int K>
__device__ __forceinline__ void kstep(const i32x4& srdA, int voA, int kt,
    const u16* __restrict__ p0, const u16* __restrict__ p1,
    const u16* __restrict__ p2, const u16* __restrict__ p3,
    int lo, f32x4 (&acc)[2][4]) {
  i32x4 a0 = llvm_amdgcn_raw_buffer_load_i32x4(srdA, voA + kt * 64, 0, AUX_SC0);
  i32x4 a1 = llvm_amdgcn_raw_buffer_load_i32x4(srdA, voA + 16 * K * 2 + kt * 64, 0, AUX_SC0);
  u16x8 b0 = *(const u16x8*)(p0 + (size_t)kt * 512 + lo);
  u16x8 b1 = *(const u16x8*)(p1 + (size_t)kt * 512 + lo);
  u16x8 b2 = *(const u16x8*)(p2 + (size_t)kt * 512 + lo);
  u16x8 b3 = *(const u16x8*)(p3 + (size_t)kt * 512 + lo);
  bf16x8 fa0 = __builtin_bit_cast(bf16x8, a0);
  bf16x8 fa1 = __builtin_bit_cast(bf16x8, a1);
  bf16x8 fb0 = __builtin_bit_cast(bf16x8, b0);
  bf16x8 fb1 = __builtin_bit_cast(bf16x8, b1);
  bf16x8 fb2 = __builtin_bit_cast(bf16x8, b2);
  bf16x8 fb3 = __builtin_bit_cast(bf16x8, b3);
  acc[0][0] = __builtin_amdgcn_mfma_f32_16x16x32_bf16(fa0, fb0, acc[0][0], 0, 0, 0);
  acc[0][1] = __builtin_amdgcn_mfma_f32_16x16x32_bf16(fa0, fb1, acc[0][1], 0, 0, 0);
  acc[0][2] = __builtin_amdgcn_mfma_f32_16x16x32_bf16(fa0, fb2, acc[0][2], 0, 0, 0);
  acc[0][3] = __builtin_amdgcn_mfma_f32_16x16x32_bf16(fa0, fb3, acc[0][3], 0, 0, 0);
  acc[1][0] = __builtin_amdgcn_mfma_f32_16x16x32_bf16(fa1, fb0, acc[1][0], 0, 0, 0);
  acc[1][1] = __builtin_amdgcn_mfma_f32_16x16x32_bf16(fa1, fb1, acc[1][1], 0, 0, 0);
  acc[1][2] = __builtin_amdgcn_mfma_f32_16x16x32_bf16(fa1, fb2, acc[1][2], 0, 0, 0);
  acc[1][3] = __builtin_amdgcn_mfma_f32_16x16x32_bf16(fa1, fb3, acc[1][3], 0, 0, 0);
}

// C[128x64] += A[128xK] @ B[Kx64]. bA: frag-cols 0,1; bB: frag-cols 2,3 (global);
// bP: LDS-resident kt<KTL prefix of frag-cols 2,3 (stride KTL). KTL=0 -> pure r0 path.
template<int K, int KTL>
__device__ __forceinline__ void gemm2(const i32x4& srdA, int voA,
    const u16* __restrict__ bA, const u16* __restrict__ bB,
    const u16* __restrict__ bP, int lane, f32x4 (&acc)[2][4]) {
  constexpr int NK = K / 32;
  const int lo = lane * 8;
  const u16* p0 = bA;
  const u16* p1 = bA + (size_t)NK * 512;
#pragma unroll 8
  for (int kt = 0; kt < KTL; ++kt)
    kstep<K>(srdA, voA, kt, p0, p1, bP, bP + (size_t)KTL * 512, lo, acc);
#pragma unroll 8
  for (int kt = KTL; kt < NK; ++kt)
    kstep<K>(srdA, voA, kt, p0, p1, bB, bB + (size_t)NK * 512, lo, acc);
}

// layer-0 job jl (0..15): stage emb(tk+1) for rows jl*8..+8, then h0'(tk) GEMM
__device__ __forceinline__ void do_l0(int tk, int xcc, int jl, bool uselds,
    const u16* __restrict__ ldsb, const u16* __restrict__ Wt0,
    const int* __restrict__ inputs, const float* __restrict__ emb,
    const float* __restrict__ b0, u16* __restrict__ A0, u16* __restrict__ A1,
    int tid)
{
  const int lane = tid & 63, w = tid >> 6, q = lane >> 4, l16 = lane & 15;
  const int c0 = jl * 64;
  if (tk < TT - 1) {
    const int grow = xcc * 128 + jl * 8 + (tid >> 5);
    const int c = (tid & 31) * 16;
    const int idx = inputs[grow * TT + tk + 1];
    const f32x4* s = (const f32x4*)(emb + (size_t)idx * EE + c);
    f32x4 f0 = s[0], f1 = s[1], f2 = s[2], f3 = s[3];
    u16x8 oa, ob;
#pragma unroll
    for (int j = 0; j < 4; ++j) {
      oa[j] = f2bf(f0[j]); oa[j + 4] = f2bf(f1[j]);
      ob[j] = f2bf(f2[j]); ob[j + 4] = f2bf(f3[j]);
    }
    u16* dst = A0 + (size_t)((tk + 1) & 1) * HN0 + (size_t)grow * K0 + c;
    *(u16x8*)dst = oa;
    *(u16x8*)(dst + 8) = ob;
  }
  if (tk < TT) {
    f32x4 acc[2][4];
#pragma unroll
    for (int i = 0; i < 2; ++i)
#pragma unroll
      for (int n = 0; n < 4; ++n) acc[i][n] = (f32x4){0.f, 0.f, 0.f, 0.f};
    i32x4 srdA = make_srd(A0 + (size_t)(tk & 1) * HN0);
    const int voA = ((xcc * 128 + w * 32 + l16) * K0 + q * 8) * 2;
    const u16* gA = Wt0 + (size_t)(c0 / 16) * NK0 * 512;
    const u16* bB = Wt0 + (size_t)(c0 / 16 + 2) * NK0 * 512;
    if (uselds) gemm2<K0, KTL0>(srdA, voA, ldsb, bB,
                                ldsb + (size_t)2 * NK0 * 512, lane, acc);
    else        gemm2<K0, 0   >(srdA, voA, gA, bB, ldsb, lane, acc);
    u16* d1 = A1 + (size_t)(tk & 1) * HN1;              // h0' -> layer-1 input (same XCD)
    u16* d2 = A0 + (size_t)((tk + 1) & 1) * HN0 + 512;  // h0 recurrent
#pragma unroll
    for (int n = 0; n < 4; ++n) {
      const int col = c0 + n * 16 + l16;
      const float bs = b0[col];
#pragma unroll
      for (int i = 0; i < 2; ++i) {
#pragma unroll
        for (int rr = 0; rr < 4; ++rr) {
          const int grow = xcc * 128 + w * 32 + i * 16 + q * 4 + rr;
          const u16 v = f2bf(fast_tanh(acc[i][n][rr] + bs));
          d1[(size_t)grow * K1 + col] = v;
          d2[(size_t)grow * K0 + col] = v;
        }
      }
    }
  }
}

// layer-1 job jl (0..15): h1(tk-1) GEMM
__device__ __forceinline__ void do_l1(int tk, int xcc, int jl, bool uselds,
    const u16* __restrict__ ldsb, const u16* __restrict__ Wt1,
    const float* __restrict__ b1, u16* __restrict__ A1, int tid)
{
  const int lane = tid & 63, w = tid >> 6, q = lane >> 4, l16 = lane & 15;
  const int c0 = jl * 64;
  f32x4 acc[2][4];
#pragma unroll
  for (int i = 0; i < 2; ++i)
#pragma unroll
    for (int n = 0; n < 4; ++n) acc[i][n] = (f32x4){0.f, 0.f, 0.f, 0.f};
  i32x4 srdA = make_srd(A1 + (size_t)((tk - 1) & 1) * HN1);
  const int voA = ((xcc * 128 + w * 32 + l16) * K1 + q * 8) * 2;
  const u16* gA = Wt1 + (size_t)(c0 / 16) * NK1 * 512;
  const u16* bB = Wt1 + (size_t)(c0 / 16 + 2) * NK1 * 512;
  if (uselds) gemm2<K1, KTL1>(srdA, voA, ldsb, bB,
                              ldsb + (size_t)2 * NK1 * 512, lane, acc);
  else        gemm2<K1, 0   >(srdA, voA, gA, bB, ldsb, lane, acc);
  u16* d1 = A1 + (size_t)(tk & 1) * HN1 + 1024;         // h1 recurrent
#pragma unroll
  for (int n = 0; n < 4; ++n) {
    const int col = c0 + n * 16 + l16;
    const float bs = b1[col];
#pragma unroll
    for (int i = 0; i < 2; ++i) {
#pragma unroll
      for (int rr = 0; rr < 4; ++rr) {
        const int grow = xcc * 128 + w * 32 + i * 16 + q * 4 + rr;
        d1[(size_t)grow * K1 + col] = f2bf(fast_tanh(acc[i][n][rr] + bs));
      }
    }
  }
}

__global__ __launch_bounds__(NTHR, 1)
void rnn_kernel(const int* __restrict__ inputs, const float* __restrict__ emb,
    const float* __restrict__ W0, const float* __restrict__ U0, const float* __restrict__ b0,
    const float* __restrict__ W1, const float* __restrict__ U1, const float* __restrict__ b1,
    const float* __restrict__ Wout, const float* __restrict__ bout,
    float* __restrict__ out,
    u16* __restrict__ Wt0, u16* __restrict__ Wt1,
    u16* __restrict__ A0, u16* __restrict__ A1, int* __restrict__ bar)
{
  extern __shared__ u16 lds[];
  int* li = (int*)lds;
  cg::grid_group grid = cg::this_grid();
  const int tid = threadIdx.x, bid = blockIdx.x;

  // ---- startup (grid-distributed): weights, emb(0), zero states + barrier area ----
  const int gstart = bid * NTHR + tid;
  wfill<K0, 512>(Wt0, W0, U0, gstart);
  wfill<K1, 1024>(Wt1, W1, U1, gstart);
  for (int g = gstart; g < BB * EE / 8; g += NBLK * NTHR) {
    const int b = g >> 6, seg = g & 63;
    const int idx = inputs[b * TT];
    const f32x4* s = (const f32x4*)(emb + (size_t)idx * EE + seg * 8);
    f32x4 f0 = s[0], f1 = s[1];
    u16x8 o;
#pragma unroll
    for (int j = 0; j < 4; ++j) { o[j] = f2bf(f0[j]); o[j + 4] = f2bf(f1[j]); }
    *(u16x8*)(A0 + (size_t)b * K0 + seg * 8) = o;
  }
  {
    const u16x8 z = {0, 0, 0, 0, 0, 0, 0, 0};
    for (int g = gstart; g < BB * 1024 / 8; g += NBLK * NTHR) {
      const int b = g >> 7, seg = g & 127;
      *(u16x8*)(A0 + (size_t)b * K0 + 512 + seg * 8) = z;      // h0(-1) = 0
      *(u16x8*)(A1 + (size_t)b * K1 + 1024 + seg * 8) = z;     // h1(-1) = 0
    }
  }
  if (bid == 0) for (int i = tid; i < BAR_INTS; i += NTHR) bar[i] = 0;
  grid.sync();

  // ---- roster: true XCD + slot; second sync publishes per-XCD counts ----
  if (tid == 0) {
    const int xc = __builtin_amdgcn_s_getreg((7 << 11) | 20) & 7;   // HW_REG_XCC_ID
    li[0] = xc;
    li[1] = atomicAdd(&bar[ROSTER_BASE + xc], 1);
  }
  __syncthreads();
  const int xcc = li[0], slot = li[1];
  __syncthreads();
  grid.sync();
  if (tid == 0)
    li[0] = __hip_atomic_load(&bar[ROSTER_BASE + xcc],
                              __ATOMIC_RELAXED, __HIP_MEMORY_SCOPE_AGENT);
  __syncthreads();
  const int nx = li[0];
  __syncthreads();

  // ---- primary job's weights -> LDS: bA (2 frag-cols, r0-proven) + bB kt-prefix ----
  if (slot < 32) {
    const bool pL0 = slot < 16;
    const int cb = (pL0 ? slot : slot - 16) * 4;
    const int NKp = pL0 ? NK0 : NK1;
    const int KTLp = pL0 ? KTL0 : KTL1;
    const u16* W = pL0 ? Wt0 : Wt1;
    const u16x8* s = (const u16x8*)(W + (size_t)cb * NKp * 512);
    const int nv = 2 * NKp * 64;
    u16x8* d = (u16x8*)lds;
    for (int i = tid; i < nv; i += NTHR) d[i] = s[i];
    // bB prefix: frag-cols cb+2, cb+3 for kt < KTLp; dest layout (f*KTLp + kt)*512 + lane*8
    u16x8* d2 = d + nv;
    const int nv2 = 2 * KTLp * 64;
    for (int i = tid; i < nv2; i += NTHR) {
      const int f = i / (KTLp * 64);
      const int rem = i - f * (KTLp * 64);
      d2[i] = *((const u16x8*)(W + (size_t)(cb + 2 + f) * NKp * 512) + rem);
    }
  }
  __syncthreads();

  // ---- tick loop: jobs 0..15 = layer0 stripes, 16..31 = layer1 stripes (lagged) ----
  for (int tk = 0; tk <= TT; ++tk) {
    for (int job = slot; job < 32; job += nx) {
      const bool uselds = (job == slot);
      if (job < 16) do_l0(tk, xcc, job, uselds, lds, Wt0, inputs, emb, b0, A0, A1, tid);
      else if (tk >= 1) do_l1(tk, xcc, job - 16, uselds, lds, Wt1, b1, A1, tid);
    }
    xbar(bar, xcc, slot, nx, tk + 1, tid);
  }

  // ---- output (slot 0 per XCD): sigmoid(h1(255) @ Wout + bout) for 128 local rows ----
  if (slot == 0) {
    const int lane = tid & 63, w = tid >> 6;
    i32x4 srdH = make_srd(A1);
    const f32x4* wv = (const f32x4*)(Wout + lane * 16);
    f32x4 w0 = wv[0], w1 = wv[1], w2 = wv[2], w3 = wv[3];
    for (int rr = 0; rr < 32; ++rr) {
      const int grow = xcc * 128 + w * 32 + rr;
      const int vo = (grow * K1 + 1024 + lane * 16) * 2;
      i32x4 hv0 = llvm_amdgcn_raw_buffer_load_i32x4(srdH, vo, 0, AUX_SC0);
      i32x4 hv1 = llvm_amdgcn_raw_buffer_load_i32x4(srdH, vo + 16, 0, AUX_SC0);
      u16x8 lo = __builtin_bit_cast(u16x8, hv0);
      u16x8 hi = __builtin_bit_cast(u16x8, hv1);
      float s = 0.f;
#pragma unroll
      for (int j = 0; j < 4; ++j) {
        s += bf2f(lo[j]) * w0[j];
        s += bf2f(lo[j + 4]) * w1[j];
        s += bf2f(hi[j]) * w2[j];
        s += bf2f(hi[j + 4]) * w3[j];
      }
#pragma unroll
      for (int off = 32; off > 0; off >>= 1) s += __shfl_down(s, off);
      if (lane == 0) out[grow] = 1.f / (1.f + expf(-(s + bout[0])));
    }
  }
}

extern "C" void kernel_launch(void* const* d_in, const int* in_sizes, int n_in,
                              void* d_out, int out_size, void* d_ws, size_t ws_size,
                              hipStream_t stream)
{
  (void)in_sizes; (void)n_in; (void)out_size; (void)ws_size;
  const int*   inputs = (const int*)d_in[0];
  const float* emb    = (const float*)d_in[1];
  const float* W0     = (const float*)d_in[2];
  const float* U0     = (const float*)d_in[3];
  const float* b0     = (const float*)d_in[4];
  const float* W1     = (const float*)d_in[5];
  const float* U1     = (const float*)d_in[6];
  const float* b1     = (const float*)d_in[7];
  const float* Wout   = (const float*)d_in[8];
  const float* bout   = (const float*)d_in[9];
  float* out = (float*)d_out;

  // ws (u16): Wt0 [1024*K0], Wt1 [1024*K1], A0 [2][1024*K0], A1 [2][1024*K1], bar
  u16* Wt0 = (u16*)d_ws;
  u16* Wt1 = Wt0 + (size_t)1024 * K0;
  u16* A0  = Wt1 + (size_t)1024 * K1;
  u16* A1  = A0 + (size_t)2 * 1024 * K0;
  int* bar = (int*)(A1 + (size_t)2 * 1024 * K1);

  static int lds_set = 0;
  if (!lds_set) {
    hipFuncSetAttribute((const void*)rnn_kernel,
                        hipFuncAttributeMaxDynamicSharedMemorySize, LDS_BYTES);
    lds_set = 1;
  }

  void* args[] = { &inputs, &emb, &W0, &U0, &b0, &W1, &U1, &b1, &Wout, &bout,
                   &out, &Wt0, &Wt1, &A0, &A1, &bar };
  hipLaunchCooperativeKernel((void*)rnn_kernel, dim3(NBLK), dim3(NTHR), args, LDS_BYTES, stream);
}

// Round 4
// 6403.283 us; speedup vs baseline: 1.3362x; 1.1266x over previous
//
#include <hip/hip_runtime.h>
#include <hip/hip_cooperative_groups.h>
#include <math.h>

namespace cg = cooperative_groups;

typedef unsigned short u16;
typedef __bf16 bf16x8 __attribute__((ext_vector_type(8)));
typedef float f32x4 __attribute__((ext_vector_type(4)));
typedef unsigned short u16x8 __attribute__((ext_vector_type(8)));
typedef int i32x4 __attribute__((ext_vector_type(4)));

#define NBLK 256
#define NTHR 512         // 8 waves, row-split: 2 waves/SIMD interleave VMEM exposure
#define BB 1024
#define TT 256
#define EE 512
#define UU 1024
#define K0 1536          // A0 row: [emb(512) | h0(1024)]
#define K1 2048          // A1 row: [h0'(1024) | h1(1024)]
#define NK0 48           // K0/32
#define NK1 64           // K1/32
#define KTL0 32          // L0: bB kt-prefix resident in LDS (of 48)
#define KTL1 16          // L1: bB kt-prefix resident in LDS (of 64)
#define HN0 ((size_t)BB * K0)
#define HN1 ((size_t)BB * K1)
// LDS: bA 2 frag-cols (L0 96KB / L1 128KB) + bB prefix (L0 64KB / L1 32KB) = 160KB
#define LDS_BYTES 163840

// bar layout (ints)
#define ROSTER_BASE 0            // [0..7] per-XCD block count
#define FLAG_BASE 32             // 8 * 256 arrival flags
#define EPOCH_BASE (32 + 2048)   // 8 epochs, 32-int stride
#define BAR_INTS 2560

#define AUX_SC0 1        // bypass L1, served by local L2

__device__ i32x4 llvm_amdgcn_raw_buffer_load_i32x4(i32x4 srsrc, int voffset, int soffset,
                                                   int aux) __asm("llvm.amdgcn.raw.buffer.load.v4i32");

__device__ __forceinline__ i32x4 make_srd(const void* p) {
  union { const void* p; int i[2]; } u; u.p = p;
  i32x4 r; r.x = u.i[0]; r.y = u.i[1]; r.z = -1; r.w = 0x00020000;
  return r;
}

__device__ __forceinline__ u16 f2bf(float f) {
  unsigned u = __builtin_bit_cast(unsigned, f);
  u += 0x7fffu + ((u >> 16) & 1u);
  return (u16)(u >> 16);
}
__device__ __forceinline__ float bf2f(u16 h) {
  return __builtin_bit_cast(float, ((unsigned)h) << 16);
}
__device__ __forceinline__ float fast_tanh(float x) {
  x = fminf(fmaxf(x, -15.f), 15.f);
  float e = __expf(2.f * x);
  return (e - 1.f) / (e + 1.f);
}

// weight transpose + MFMA-fragment swizzle (r2/r3-verified layout):
// elem g = (cb*NK + kt)*64 + lane (8 u16 each); value = Wfull[k][n],
// n = cb*16 + (lane&15), k = kt*32 + (lane>>4)*8 + e
template<int K, int KLOW>
__device__ __forceinline__ void wfill(u16* __restrict__ Wt,
    const float* __restrict__ Wl, const float* __restrict__ Wh, int gstart) {
  constexpr int NK = K / 32;
  constexpr int NG = 1024 * K / 8;
  for (int g = gstart; g < NG; g += NBLK * NTHR) {
    const int lane = g & 63;
    const int r = g >> 6;
    const int kt = r % NK;
    const int cb = r / NK;
    const int n = cb * 16 + (lane & 15);
    const int kb = kt * 32 + (lane >> 4) * 8;
    u16x8 o;
#pragma unroll
    for (int e = 0; e < 8; ++e) {
      const int k = kb + e;
      const float v = (k < KLOW) ? Wl[(size_t)k * UU + n] : Wh[(size_t)(k - KLOW) * UU + n];
      o[e] = f2bf(v);
    }
    *(u16x8*)(Wt + (size_t)g * 8) = o;
  }
}

// XCD-local barrier: agent-scope flags + leader + epoch; guarded polls bail instead of hanging.
__device__ __forceinline__ void xbar(int* __restrict__ bar, int xcc, int slot, int nx,
                                     int tgt, int tid) {
  __syncthreads();   // all waves' stores drained before arrival
  if (tid < 64) {
    if (tid == 0)
      __hip_atomic_store(&bar[FLAG_BASE + xcc * 256 + slot], tgt,
                         __ATOMIC_RELAXED, __HIP_MEMORY_SCOPE_AGENT);
    if (slot == 0) {
      for (int base = 0; base < nx; base += 64) {
        const int i = base + tid;
        const bool act = (i < nx);
        int guard = 0;
        bool done = false;
        do {
          int v = act ? __hip_atomic_load(&bar[FLAG_BASE + xcc * 256 + i],
                                          __ATOMIC_RELAXED, __HIP_MEMORY_SCOPE_AGENT)
                      : tgt;
          done = __all(v >= tgt) != 0;
        } while (!done && ++guard < 300000);
      }
      if (tid == 0)
        __hip_atomic_store(&bar[EPOCH_BASE + xcc * 32], tgt,
                           __ATOMIC_RELAXED, __HIP_MEMORY_SCOPE_AGENT);
    } else if (tid == 0) {
      int guard = 0;
      while (__hip_atomic_load(&bar[EPOCH_BASE + xcc * 32],
                               __ATOMIC_RELAXED, __HIP_MEMORY_SCOPE_AGENT) < tgt
             && ++guard < 600000)
        __builtin_amdgcn_s_sleep(8);
    }
  }
  __syncthreads();
}

// one kt step (row-split): 1 A buffer-load (16 rows), 4 B pointer-loads, 4 MFMA.
template<int K>
__device__ __forceinline__ void kstep(const i32x4& srdA, int voA, int kt,
    const u16* __restrict__ p0, const u16* __restrict__ p1,
    const u16* __restrict__ p2, const u16* __restrict__ p3,
    int lo, f32x4 (&acc)[4]) {
  i32x4 a0 = llvm_amdgcn_raw_buffer_load_i32x4(srdA, voA + kt * 64, 0, AUX_SC0);
  u16x8 b0 = *(const u16x8*)(p0 + (size_t)kt * 512 + lo);
  u16x8 b1 = *(const u16x8*)(p1 + (size_t)kt * 512 + lo);
  u16x8 b2 = *(const u16x8*)(p2 + (size_t)kt * 512 + lo);
  u16x8 b3 = *(const u16x8*)(p3 + (size_t)kt * 512 + lo);
  bf16x8 fa0 = __builtin_bit_cast(bf16x8, a0);
  bf16x8 fb0 = __builtin_bit_cast(bf16x8, b0);
  bf16x8 fb1 = __builtin_bit_cast(bf16x8, b1);
  bf16x8 fb2 = __builtin_bit_cast(bf16x8, b2);
  bf16x8 fb3 = __builtin_bit_cast(bf16x8, b3);
  acc[0] = __builtin_amdgcn_mfma_f32_16x16x32_bf16(fa0, fb0, acc[0], 0, 0, 0);
  acc[1] = __builtin_amdgcn_mfma_f32_16x16x32_bf16(fa0, fb1, acc[1], 0, 0, 0);
  acc[2] = __builtin_amdgcn_mfma_f32_16x16x32_bf16(fa0, fb2, acc[2], 0, 0, 0);
  acc[3] = __builtin_amdgcn_mfma_f32_16x16x32_bf16(fa0, fb3, acc[3], 0, 0, 0);
}

// C[16x64] += A[16xK] @ B[Kx64] (per wave). bA: frag-cols 0,1; bB: frag-cols 2,3
// (global); bP: LDS-resident kt<KTL prefix of frag-cols 2,3 (stride KTL).
template<int K, int KTL>
__device__ __forceinline__ void gemm2(const i32x4& srdA, int voA,
    const u16* __restrict__ bA, const u16* __restrict__ bB,
    const u16* __restrict__ bP, int lane, f32x4 (&acc)[4]) {
  constexpr int NK = K / 32;
  const int lo = lane * 8;
  const u16* p0 = bA;
  const u16* p1 = bA + (size_t)NK * 512;
#pragma unroll 8
  for (int kt = 0; kt < KTL; ++kt)
    kstep<K>(srdA, voA, kt, p0, p1, bP, bP + (size_t)KTL * 512, lo, acc);
#pragma unroll 8
  for (int kt = KTL; kt < NK; ++kt)
    kstep<K>(srdA, voA, kt, p0, p1, bB, bB + (size_t)NK * 512, lo, acc);
}

// layer-0 job jl (0..15): stage emb(tk+1) for rows jl*8..+8, then h0'(tk) GEMM
__device__ __forceinline__ void do_l0(int tk, int xcc, int jl, bool uselds,
    const u16* __restrict__ ldsb, const u16* __restrict__ Wt0,
    const int* __restrict__ inputs, const float* __restrict__ emb,
    const float* __restrict__ b0, u16* __restrict__ A0, u16* __restrict__ A1,
    int tid)
{
  const int lane = tid & 63, w = tid >> 6, q = lane >> 4, l16 = lane & 15;
  const int c0 = jl * 64;
  if (tk < TT - 1) {
    // 512 threads: 8 rows x 64 threads, 8 f32 -> 8 bf16 each
    const int grow = xcc * 128 + jl * 8 + (tid >> 6);
    const int c = (tid & 63) * 8;
    const int idx = inputs[grow * TT + tk + 1];
    const f32x4* s = (const f32x4*)(emb + (size_t)idx * EE + c);
    f32x4 f0 = s[0], f1 = s[1];
    u16x8 oa;
#pragma unroll
    for (int j = 0; j < 4; ++j) { oa[j] = f2bf(f0[j]); oa[j + 4] = f2bf(f1[j]); }
    *(u16x8*)(A0 + (size_t)((tk + 1) & 1) * HN0 + (size_t)grow * K0 + c) = oa;
  }
  if (tk < TT) {
    f32x4 acc[4];
#pragma unroll
    for (int n = 0; n < 4; ++n) acc[n] = (f32x4){0.f, 0.f, 0.f, 0.f};
    i32x4 srdA = make_srd(A0 + (size_t)(tk & 1) * HN0);
    const int voA = ((xcc * 128 + w * 16 + l16) * K0 + q * 8) * 2;
    const u16* gA = Wt0 + (size_t)(c0 / 16) * NK0 * 512;
    const u16* bB = Wt0 + (size_t)(c0 / 16 + 2) * NK0 * 512;
    if (uselds) gemm2<K0, KTL0>(srdA, voA, ldsb, bB,
                                ldsb + (size_t)2 * NK0 * 512, lane, acc);
    else        gemm2<K0, 0   >(srdA, voA, gA, bB, ldsb, lane, acc);
    u16* d1 = A1 + (size_t)(tk & 1) * HN1;              // h0' -> layer-1 input (same XCD)
    u16* d2 = A0 + (size_t)((tk + 1) & 1) * HN0 + 512;  // h0 recurrent
#pragma unroll
    for (int n = 0; n < 4; ++n) {
      const int col = c0 + n * 16 + l16;
      const float bs = b0[col];
#pragma unroll
      for (int rr = 0; rr < 4; ++rr) {
        const int grow = xcc * 128 + w * 16 + q * 4 + rr;
        const u16 v = f2bf(fast_tanh(acc[n][rr] + bs));
        d1[(size_t)grow * K1 + col] = v;
        d2[(size_t)grow * K0 + col] = v;
      }
    }
  }
}

// layer-1 job jl (0..15): h1(tk-1) GEMM
__device__ __forceinline__ void do_l1(int tk, int xcc, int jl, bool uselds,
    const u16* __restrict__ ldsb, const u16* __restrict__ Wt1,
    const float* __restrict__ b1, u16* __restrict__ A1, int tid)
{
  const int lane = tid & 63, w = tid >> 6, q = lane >> 4, l16 = lane & 15;
  const int c0 = jl * 64;
  f32x4 acc[4];
#pragma unroll
  for (int n = 0; n < 4; ++n) acc[n] = (f32x4){0.f, 0.f, 0.f, 0.f};
  i32x4 srdA = make_srd(A1 + (size_t)((tk - 1) & 1) * HN1);
  const int voA = ((xcc * 128 + w * 16 + l16) * K1 + q * 8) * 2;
  const u16* gA = Wt1 + (size_t)(c0 / 16) * NK1 * 512;
  const u16* bB = Wt1 + (size_t)(c0 / 16 + 2) * NK1 * 512;
  if (uselds) gemm2<K1, KTL1>(srdA, voA, ldsb, bB,
                              ldsb + (size_t)2 * NK1 * 512, lane, acc);
  else        gemm2<K1, 0   >(srdA, voA, gA, bB, ldsb, lane, acc);
  u16* d1 = A1 + (size_t)(tk & 1) * HN1 + 1024;         // h1 recurrent
#pragma unroll
  for (int n = 0; n < 4; ++n) {
    const int col = c0 + n * 16 + l16;
    const float bs = b1[col];
#pragma unroll
    for (int rr = 0; rr < 4; ++rr) {
      const int grow = xcc * 128 + w * 16 + q * 4 + rr;
      d1[(size_t)grow * K1 + col] = f2bf(fast_tanh(acc[n][rr] + bs));
    }
  }
}

__global__ __launch_bounds__(NTHR, 1)
void rnn_kernel(const int* __restrict__ inputs, const float* __restrict__ emb,
    const float* __restrict__ W0, const float* __restrict__ U0, const float* __restrict__ b0,
    const float* __restrict__ W1, const float* __restrict__ U1, const float* __restrict__ b1,
    const float* __restrict__ Wout, const float* __restrict__ bout,
    float* __restrict__ out,
    u16* __restrict__ Wt0, u16* __restrict__ Wt1,
    u16* __restrict__ A0, u16* __restrict__ A1, int* __restrict__ bar)
{
  extern __shared__ u16 lds[];
  int* li = (int*)lds;
  cg::grid_group grid = cg::this_grid();
  const int tid = threadIdx.x, bid = blockIdx.x;

  // ---- startup (grid-distributed): weights, emb(0), zero states + barrier area ----
  const int gstart = bid * NTHR + tid;
  wfill<K0, 512>(Wt0, W0, U0, gstart);
  wfill<K1, 1024>(Wt1, W1, U1, gstart);
  for (int g = gstart; g < BB * EE / 8; g += NBLK * NTHR) {
    const int b = g >> 6, seg = g & 63;
    const int idx = inputs[b * TT];
    const f32x4* s = (const f32x4*)(emb + (size_t)idx * EE + seg * 8);
    f32x4 f0 = s[0], f1 = s[1];
    u16x8 o;
#pragma unroll
    for (int j = 0; j < 4; ++j) { o[j] = f2bf(f0[j]); o[j + 4] = f2bf(f1[j]); }
    *(u16x8*)(A0 + (size_t)b * K0 + seg * 8) = o;
  }
  {
    const u16x8 z = {0, 0, 0, 0, 0, 0, 0, 0};
    for (int g = gstart; g < BB * 1024 / 8; g += NBLK * NTHR) {
      const int b = g >> 7, seg = g & 127;
      *(u16x8*)(A0 + (size_t)b * K0 + 512 + seg * 8) = z;      // h0(-1) = 0
      *(u16x8*)(A1 + (size_t)b * K1 + 1024 + seg * 8) = z;     // h1(-1) = 0
    }
  }
  if (bid == 0) for (int i = tid; i < BAR_INTS; i += NTHR) bar[i] = 0;
  grid.sync();

  // ---- roster: true XCD + slot; second sync publishes per-XCD counts ----
  if (tid == 0) {
    const int xc = __builtin_amdgcn_s_getreg((7 << 11) | 20) & 7;   // HW_REG_XCC_ID
    li[0] = xc;
    li[1] = atomicAdd(&bar[ROSTER_BASE + xc], 1);
  }
  __syncthreads();
  const int xcc = li[0], slot = li[1];
  __syncthreads();
  grid.sync();
  if (tid == 0)
    li[0] = __hip_atomic_load(&bar[ROSTER_BASE + xcc],
                              __ATOMIC_RELAXED, __HIP_MEMORY_SCOPE_AGENT);
  __syncthreads();
  const int nx = li[0];
  __syncthreads();

  // ---- primary job's weights -> LDS: bA (2 frag-cols) + bB kt-prefix (tick-invariant) ----
  if (slot < 32) {
    const bool pL0 = slot < 16;
    const int cb = (pL0 ? slot : slot - 16) * 4;
    const int NKp = pL0 ? NK0 : NK1;
    const int KTLp = pL0 ? KTL0 : KTL1;
    const u16* W = pL0 ? Wt0 : Wt1;
    const u16x8* s = (const u16x8*)(W + (size_t)cb * NKp * 512);
    const int nv = 2 * NKp * 64;
    u16x8* d = (u16x8*)lds;
    for (int i = tid; i < nv; i += NTHR) d[i] = s[i];
    // bB prefix: frag-cols cb+2, cb+3 for kt < KTLp; dest layout (f*KTLp + kt)*512 + lane*8
    u16x8* d2 = d + nv;
    const int nv2 = 2 * KTLp * 64;
    for (int i = tid; i < nv2; i += NTHR) {
      const int f = i / (KTLp * 64);
      const int rem = i - f * (KTLp * 64);
      d2[i] = *((const u16x8*)(W + (size_t)(cb + 2 + f) * NKp * 512) + rem);
    }
  }
  __syncthreads();

  // ---- tick loop: jobs 0..15 = layer0 stripes, 16..31 = layer1 stripes (lagged) ----
  for (int tk = 0; tk <= TT; ++tk) {
    for (int job = slot; job < 32; job += nx) {
      const bool uselds = (job == slot);
      if (job < 16) do_l0(tk, xcc, job, uselds, lds, Wt0, inputs, emb, b0, A0, A1, tid);
      else if (tk >= 1) do_l1(tk, xcc, job - 16, uselds, lds, Wt1, b1, A1, tid);
    }
    xbar(bar, xcc, slot, nx, tk + 1, tid);
  }

  // ---- output (slot 0 per XCD): sigmoid(h1(255) @ Wout + bout) for 128 local rows ----
  if (slot == 0) {
    const int lane = tid & 63, w = tid >> 6;   // 8 waves x 16 rows
    i32x4 srdH = make_srd(A1);
    const f32x4* wv = (const f32x4*)(Wout + lane * 16);
    f32x4 w0 = wv[0], w1 = wv[1], w2 = wv[2], w3 = wv[3];
    for (int rr = 0; rr < 16; ++rr) {
      const int grow = xcc * 128 + w * 16 + rr;
      const int vo = (grow * K1 + 1024 + lane * 16) * 2;
      i32x4 hv0 = llvm_amdgcn_raw_buffer_load_i32x4(srdH, vo, 0, AUX_SC0);
      i32x4 hv1 = llvm_amdgcn_raw_buffer_load_i32x4(srdH, vo + 16, 0, AUX_SC0);
      u16x8 lo = __builtin_bit_cast(u16x8, hv0);
      u16x8 hi = __builtin_bit_cast(u16x8, hv1);
      float s = 0.f;
#pragma unroll
      for (int j = 0; j < 4; ++j) {
        s += bf2f(lo[j]) * w0[j];
        s += bf2f(lo[j + 4]) * w1[j];
        s += bf2f(hi[j]) * w2[j];
        s += bf2f(hi[j + 4]) * w3[j];
      }
#pragma unroll
      for (int off = 32; off > 0; off >>= 1) s += __shfl_down(s, off);
      if (lane == 0) out[grow] = 1.f / (1.f + expf(-(s + bout[0])));
    }
  }
}

extern "C" void kernel_launch(void* const* d_in, const int* in_sizes, int n_in,
                              void* d_out, int out_size, void* d_ws, size_t ws_size,
                              hipStream_t stream)
{
  (void)in_sizes; (void)n_in; (void)out_size; (void)ws_size;
  const int*   inputs = (const int*)d_in[0];
  const float* emb    = (const float*)d_in[1];
  const float* W0     = (const float*)d_in[2];
  const float* U0     = (const float*)d_in[3];
  const float* b0     = (const float*)d_in[4];
  const float* W1     = (const float*)d_in[5];
  const float* U1     = (const float*)d_in[6];
  const float* b1     = (const float*)d_in[7];
  const float* Wout   = (const float*)d_in[8];
  const float* bout   = (const float*)d_in[9];
  float* out = (float*)d_out;

  // ws (u16): Wt0 [1024*K0], Wt1 [1024*K1], A0 [2][1024*K0], A1 [2][1024*K1], bar
  u16* Wt0 = (u16*)d_ws;
  u16* Wt1 = Wt0 + (size_t)1024 * K0;
  u16* A0  = Wt1 + (size_t)1024 * K1;
  u16* A1  = A0 + (size_t)2 * 1024 * K0;
  int* bar = (int*)(A1 + (size_t)2 * 1024 * K1);

  static int lds_set = 0;
  if (!lds_set) {
    hipFuncSetAttribute((const void*)rnn_kernel,
                        hipFuncAttributeMaxDynamicSharedMemorySize, LDS_BYTES);
    lds_set = 1;
  }

  void* args[] = { &inputs, &emb, &W0, &U0, &b0, &W1, &U1, &b1, &Wout, &bout,
                   &out, &Wt0, &Wt1, &A0, &A1, &bar };
  hipLaunchCooperativeKernel((void*)rnn_kernel, dim3(NBLK), dim3(NTHR), args, LDS_BYTES, stream);
}